// Round 16
// baseline (628.163 us; speedup 1.0000x reference)
//
#include <hip/hip_runtime.h>
#include <hip/hip_bf16.h>
#include <stdint.h>
#include <math.h>

#define S_LEN 2048
#define NHEAD 32
#define NKVH  8
#define HDIM  128
#define HID   4096

typedef __attribute__((ext_vector_type(4))) float f32x4;
typedef __attribute__((ext_vector_type(8))) short s16x8;
typedef __attribute__((ext_vector_type(4))) short s16x4;

__device__ __forceinline__ float bf2f(ushort u){
  union { float f; uint32_t i; } c; c.i = ((uint32_t)u) << 16; return c.f;
}
__device__ __forceinline__ ushort f2bf(float f){
  union { float f; uint32_t i; } c; c.f = f;
  uint32_t i = c.i;
  return (ushort)((i + 0x7FFFu + ((i >> 16) & 1u)) >> 16);
}

// ---------------- weight transpose-convert body: W f32[K,N] -> WT bf16[N,K] ----------------
__device__ __forceinline__ void wtrans_body(const float* __restrict__ W, ushort* __restrict__ WT,
                                            int K, int N, int k0, int n0, int tid){
  __shared__ float T[64][68];
  #pragma unroll
  for (int it = 0; it < 4; ++it){
    int slot = it*256 + tid;
    int kr = slot >> 4, c4 = slot & 15;
    f32x4 v = *(const f32x4*)(W + (size_t)(k0 + kr) * N + n0 + c4*4);
    *(f32x4*)&T[kr][c4*4] = v;
  }
  __syncthreads();
  #pragma unroll
  for (int it = 0; it < 2; ++it){
    int slot = it*256 + tid;
    int nr = slot >> 3, k8 = slot & 7;
    s16x8 o;
    #pragma unroll
    for (int j = 0; j < 8; ++j) o[j] = f2bf(T[k8*8 + j][nr]);
    *(s16x8*)(WT + (size_t)(n0 + nr) * K + k0 + k8*8) = o;
  }
}

// fused prep: y<64 Wq, 64..79 Wk, 80..95 Wv, 96..159 Wo transpose; y>=160: X cvt + RoPE table
__global__ void prep_k(const float* __restrict__ Wq, const float* __restrict__ Wk,
                       const float* __restrict__ Wv, const float* __restrict__ Wo,
                       ushort* __restrict__ WqT, ushort* __restrict__ WkvT,
                       ushort* __restrict__ WoT,
                       const float* __restrict__ X, ushort* __restrict__ Xb,
                       float* __restrict__ cost, float* __restrict__ sint){
  int y = blockIdx.y;
  if (y < 160){
    const float* W; ushort* WT; int N, n0;
    if (y < 64){ W = Wq; WT = WqT;  N = 4096; n0 = y*64; }
    else if (y < 80){ W = Wk; WT = WkvT; N = 1024; n0 = (y-64)*64; }
    else if (y < 96){ W = Wv; WT = WkvT + (size_t)1024*HID; N = 1024; n0 = (y-80)*64; }
    else { W = Wo; WT = WoT; N = 4096; n0 = (y-96)*64; }
    wtrans_body(W, WT, HID, N, blockIdx.x*64, n0, threadIdx.x);
  } else {
    int cid = (y - 160) * 64 + blockIdx.x;    // 0..8191
    int ri = cid * 256 + threadIdx.x;
    if (ri < S_LEN * 64){
      int s = ri >> 6, j = ri & 63;
      float invf = powf(10000.0f, -(float)j * (1.0f / 64.0f));
      float a = (float)s * invf;
      cost[ri] = cosf(a);
      sint[ri] = sinf(a);
    }
    size_t i = ((size_t)cid * 256 + threadIdx.x) * 8;
    f32x4 a = *(const f32x4*)(X + i);
    f32x4 b = *(const f32x4*)(X + i + 4);
    s16x8 o;
    o[0]=f2bf(a[0]); o[1]=f2bf(a[1]); o[2]=f2bf(a[2]); o[3]=f2bf(a[3]);
    o[4]=f2bf(b[0]); o[5]=f2bf(b[1]); o[6]=f2bf(b[2]); o[7]=f2bf(b[3]);
    *(s16x8*)(Xb + i) = o;
  }
}

// ---------------- 128x128 GEMM, T2 swizzle + double-buffered 2-phase (T3 minimum) ----------------
// EPI: 0 = bf16 out, 2 = f32 out,
// EPI 3 = KV projection: cols < 1024 -> RoPE'd K into KVb; cols >= 1024 -> V packed into Vt
template<int EPI>
__global__ __launch_bounds__(256)
void gemm_bt(const ushort* __restrict__ A, const ushort* __restrict__ Bt,
             void* __restrict__ Cout, int M, int N, int K,
             const float* __restrict__ cost, const float* __restrict__ sint,
             float oscale, ushort* __restrict__ Vt)
{
  __shared__ ushort As[2][128*64];
  __shared__ ushort Bs[2][128*64];
  const int tid = threadIdx.x;
  const int w = tid >> 6, lane = tid & 63;
  const int l15 = lane & 15, l4 = lane >> 4;
  const int swz = (l15 & 7) << 4;
  const size_t Abase = (size_t)blockIdx.x * 128 * K;
  const size_t Bbase = (size_t)blockIdx.y * 128 * K;

  f32x4 acc[2][8] = {};

  const int srow = (w << 3) + (lane >> 3);
  const int scolb = ((lane & 7) * 16) ^ (((lane >> 3) & 7) << 4);
  const ushort* Agrow = A + Abase + (size_t)srow * K;
  const ushort* Bgrow = Bt + Bbase + (size_t)srow * K;

  auto STAGE = [&](int bf, int k0){
    #pragma unroll
    for (int i = 0; i < 4; ++i){
      __builtin_amdgcn_global_load_lds(
        (const __attribute__((address_space(1))) void*)((const char*)(Agrow + k0 + (size_t)(32*i)*K) + scolb),
        (__attribute__((address_space(3))) void*)((char*)As[bf] + w*1024 + i*4096), 16, 0, 0);
      __builtin_amdgcn_global_load_lds(
        (const __attribute__((address_space(1))) void*)((const char*)(Bgrow + k0 + (size_t)(32*i)*K) + scolb),
        (__attribute__((address_space(3))) void*)((char*)Bs[bf] + w*1024 + i*4096), 16, 0, 0);
    }
  };

  const int nt = K >> 6;
  int cur = 0;
  STAGE(0, 0);
  __syncthreads();

  for (int t = 0; t < nt; ++t){
    if (t + 1 < nt) STAGE(cur ^ 1, (t + 1) * 64);
    #pragma unroll
    for (int kk = 0; kk < 2; ++kk){
      s16x8 af[2], bfr[8];
      #pragma unroll
      for (int m = 0; m < 2; ++m)
        af[m] = *(const s16x8*)((char*)As[cur] + (w*32 + m*16 + l15)*128 + ((kk*64 + l4*16) ^ swz));
      #pragma unroll
      for (int n = 0; n < 8; ++n)
        bfr[n] = *(const s16x8*)((char*)Bs[cur] + (n*16 + l15)*128 + ((kk*64 + l4*16) ^ swz));
      __builtin_amdgcn_s_setprio(1);
      #pragma unroll
      for (int m = 0; m < 2; ++m)
        #pragma unroll
        for (int n = 0; n < 8; ++n)
          acc[m][n] = __builtin_amdgcn_mfma_f32_16x16x32_bf16(af[m], bfr[n], acc[m][n], 0, 0, 0);
      __builtin_amdgcn_s_setprio(0);
    }
    __syncthreads();
    cur ^= 1;
  }

  const int r0 = (int)blockIdx.x * 128 + w * 32;
  const int c0 = (int)blockIdx.y * 128;
  if (EPI == 2){
    float* C = (float*)Cout;
    #pragma unroll
    for (int m = 0; m < 2; ++m)
      #pragma unroll
      for (int r = 0; r < 4; ++r){
        size_t rowoff = (size_t)(r0 + m*16 + l4*4 + r) * N + c0;
        #pragma unroll
        for (int n = 0; n < 8; ++n)
          C[rowoff + n*16 + l15] = acc[m][n][r];
      }
  } else if (EPI == 0){
    ushort* C = (ushort*)Cout;
    #pragma unroll
    for (int m = 0; m < 2; ++m)
      #pragma unroll
      for (int r = 0; r < 4; ++r){
        size_t rowoff = (size_t)(r0 + m*16 + l4*4 + r) * N + c0;
        #pragma unroll
        for (int n = 0; n < 8; ++n)
          C[rowoff + n*16 + l15] = f2bf(acc[m][n][r]);
      }
  } else if (EPI == 3 && c0 >= 1024){
    const int kvh = (c0 - 1024) >> 7;
    #pragma unroll
    for (int m = 0; m < 2; ++m){
      int row0 = r0 + m*16 + l4*4;
      int b = row0 >> 11, s = row0 & (S_LEN - 1);
      ushort* vbase = Vt + ((size_t)(b*NKVH + kvh) * HDIM) * S_LEN + s;
      #pragma unroll
      for (int n = 0; n < 8; ++n){
        s16x4 pk;
        #pragma unroll
        for (int r = 0; r < 4; ++r) pk[r] = (short)f2bf(acc[m][n][r]);
        *(s16x4*)(vbase + (size_t)(n*16 + l15) * S_LEN) = pk;
      }
    }
  } else {
    ushort* C = (ushort*)Cout;
    #pragma unroll
    for (int m = 0; m < 2; ++m)
      #pragma unroll
      for (int r = 0; r < 4; ++r){
        int row = r0 + m*16 + l4*4 + r;
        int pos = row & (S_LEN - 1);
        size_t rowoff = (size_t)row * N + c0;
        #pragma unroll
        for (int n = 0; n < 4; ++n){
          int d = n*16 + l15;
          float cv = cost[pos*64 + d];
          float sv = sint[pos*64 + d];
          float x1 = acc[m][n][r];
          float x2 = acc[m][n+4][r];
          C[rowoff + d]      = f2bf((x1*cv - x2*sv) * oscale);
          C[rowoff + d + 64] = f2bf((x2*cv + x1*sv) * oscale);
        }
      }
  }
}

// ---------------- 256x256 8-phase GEMM (T2+T3+T4+T5), depth-3 prefetch, 1 barrier/phase ----------------
template<int EPI>
__global__ __launch_bounds__(512, 2)
void gemm256(const ushort* __restrict__ A, const ushort* __restrict__ Bt,
             void* __restrict__ Cout, int M, int N, int K,
             const float* __restrict__ cost, const float* __restrict__ sint,
             float oscale)
{
  extern __shared__ char L[];                 // 131072 B
  const int tid = threadIdx.x;
  const int wid = tid >> 6, lane = tid & 63;
  const int wm = wid >> 2, wn = wid & 3;
  const int l15 = lane & 15, l4 = lane >> 4;
  const int swz = (l15 & 7) << 4;
  const int nwg  = gridDim.x;
  const int bid  = blockIdx.x;
  const int sbid = (bid & 7) * (nwg >> 3) + (bid >> 3);
  const int gx   = sbid & 15, gy = sbid >> 4;
  const int brow = gx * 256, bcol = gy * 256;
  const int nt = K >> 6;

  f32x4 acc[8][4] = {};
  s16x8 areg[8], b0reg[4], b1reg[4];

  auto STAGE = [&](int arr, int sh, int bf, int tile){
    int tt = tile < nt ? tile : nt - 1;
    const ushort* gb = arr ? (Bt + (size_t)bcol * K) : (A + (size_t)brow * K);
    char* lb = L + bf*65536 + arr*32768;
    #pragma unroll
    for (int j = 0; j < 2; ++j){
      int c   = j*8 + wid;
      int rg0 = (c >= 8 ? 128 : 0) + sh*64 + ((c*8) & 63);
      int rg  = rg0 + (lane >> 3);
      const char* gsrc = (const char*)(gb + (size_t)rg * K + tt*64)
                       + (((lane & 7) * 16) ^ (((lane >> 3) & 7) << 4));
      __builtin_amdgcn_global_load_lds(
        (const __attribute__((address_space(1))) void*)gsrc,
        (__attribute__((address_space(3))) void*)(lb + rg0*128), 16, 0, 0);
    }
  };
  auto LDA = [&](int bf, int mh){
    const char* ab = L + bf*65536;
    #pragma unroll
    for (int i = 0; i < 4; ++i){
      int row = wm*128 + (mh*4 + i)*16 + l15;
      #pragma unroll
      for (int kk = 0; kk < 2; ++kk)
        areg[i*2+kk] = *(const s16x8*)(ab + row*128 + ((kk*64 + l4*16) ^ swz));
    }
  };
  auto LDB = [&](int bf, int nh, s16x8* breg){
    const char* bb = L + bf*65536 + 32768;
    #pragma unroll
    for (int j = 0; j < 2; ++j){
      int row = wn*64 + (nh*2 + j)*16 + l15;
      #pragma unroll
      for (int kk = 0; kk < 2; ++kk)
        breg[j*2+kk] = *(const s16x8*)(bb + row*128 + ((kk*64 + l4*16) ^ swz));
    }
  };
  auto MFMA16 = [&](int mh, int nh, s16x8* breg){
    __builtin_amdgcn_s_setprio(1);
    #pragma unroll
    for (int kk = 0; kk < 2; ++kk)
      #pragma unroll
      for (int i = 0; i < 4; ++i)
        #pragma unroll
        for (int j = 0; j < 2; ++j)
          acc[mh*4+i][nh*2+j] = __builtin_amdgcn_mfma_f32_16x16x32_bf16(
              areg[i*2+kk], breg[j*2+kk], acc[mh*4+i][nh*2+j], 0, 0, 0);
    __builtin_amdgcn_s_setprio(0);
  };

  STAGE(0,0,0,0); STAGE(1,0,0,0); STAGE(0,1,0,0); STAGE(1,1,0,0);
  STAGE(0,0,1,1); STAGE(1,0,1,1); STAGE(0,1,1,1);
  asm volatile("s_waitcnt vmcnt(6)" ::: "memory");
  __builtin_amdgcn_s_barrier();

  for (int t = 0; t < nt; t += 2){
    LDA(0,0); LDB(0,0,b0reg); STAGE(1,1,1,t+1);
    __builtin_amdgcn_s_barrier();
    MFMA16(0,0,b0reg);
    LDB(0,1,b1reg); STAGE(0,0,0,t+2);
    __builtin_amdgcn_s_barrier();
    MFMA16(0,1,b1reg);
    LDA(0,1); STAGE(1,0,0,t+2);
    __builtin_amdgcn_s_barrier();
    MFMA16(1,0,b0reg);
    STAGE(0,1,0,t+2);
    asm volatile("s_waitcnt vmcnt(6)" ::: "memory");
    __builtin_amdgcn_s_barrier();
    MFMA16(1,1,b1reg);
    LDA(1,0); LDB(1,0,b0reg); STAGE(1,1,0,t+2);
    __builtin_amdgcn_s_barrier();
    MFMA16(0,0,b0reg);
    LDB(1,1,b1reg); STAGE(0,0,1,t+3);
    __builtin_amdgcn_s_barrier();
    MFMA16(0,1,b1reg);
    LDA(1,1); STAGE(1,0,1,t+3);
    __builtin_amdgcn_s_barrier();
    MFMA16(1,0,b0reg);
    STAGE(0,1,1,t+3);
    asm volatile("s_waitcnt vmcnt(6)" ::: "memory");
    __builtin_amdgcn_s_barrier();
    MFMA16(1,1,b1reg);
  }
  asm volatile("s_waitcnt vmcnt(0)" ::: "memory");
  __builtin_amdgcn_s_barrier();

  if (EPI == 2){
    float* C = (float*)Cout;
    #pragma unroll
    for (int m = 0; m < 8; ++m)
      #pragma unroll
      for (int r = 0; r < 4; ++r){
        size_t rowoff = (size_t)(brow + wm*128 + m*16 + l4*4 + r) * N + bcol + wn*64;
        #pragma unroll
        for (int n = 0; n < 4; ++n)
          C[rowoff + n*16 + l15] = acc[m][n][r];
      }
  } else {
    float* xls = (float*)L;
    ushort* C = (ushort*)Cout;
    float* mine = xls + wid*2176;
    const float* part = xls + (wid^1)*2176;
    #pragma unroll
    for (int mm = 0; mm < 4; ++mm){
      #pragma unroll
      for (int mi = 0; mi < 2; ++mi){
        int m = mm*2 + mi;
        #pragma unroll
        for (int r = 0; r < 4; ++r)
          #pragma unroll
          for (int n = 0; n < 4; ++n)
            mine[(mi*16 + l4*4 + r)*68 + n*16 + l15] = acc[m][n][r];
      }
      __builtin_amdgcn_s_barrier();
      #pragma unroll
      for (int mi = 0; mi < 2; ++mi){
        int m = mm*2 + mi;
        #pragma unroll
        for (int r = 0; r < 4; ++r){
          int rr = brow + wm*128 + m*16 + l4*4 + r;
          int pos = rr & (S_LEN - 1);
          size_t rowoff = (size_t)rr * N + bcol + wn*64;
          #pragma unroll
          for (int n = 0; n < 4; ++n){
            int d2 = n*16 + l15;
            float x  = acc[m][n][r];
            float px = part[(mi*16 + l4*4 + r)*68 + d2];
            float cv = cost[pos*64 + d2], sv = sint[pos*64 + d2];
            float o = (wn & 1) ? (x*cv + px*sv) : (x*cv - px*sv);
            C[rowoff + d2] = f2bf(o * oscale);
          }
        }
      }
      __builtin_amdgcn_s_barrier();
    }
  }
}

// ---------------- causal GQA flash attention: merged dual-q-tile shared-KV loop ----------------
// grid 512 x 256 threads; block handles q-tiles {pair, 15-pair} in ONE kv loop
// (shared staging: nt = 2*(15-pair)+2 tiles instead of 34 across two passes).
__global__ __launch_bounds__(256, 2)
void attn_k(const ushort* __restrict__ Q, const ushort* __restrict__ KVb,
            const ushort* __restrict__ Vt, ushort* __restrict__ AO)
{
  extern __shared__ char L[];
  const int tid = threadIdx.x, w = tid >> 6, lane = tid & 63;
  const int l15 = lane & 15, l4 = lane >> 4;
  const int swz = (l15 & 7) << 4;

  const int id  = blockIdx.x;
  const int idx = id >> 3;
  const int bk  = (id & 7) * 2 + (idx & 1);   // b*8 + kvh
  const int b   = bk >> 3, kvh = bk & 7;
  const int h   = kvh * 4 + ((idx >> 1) & 3);
  const int pair= idx >> 3;                   // 0..7
  const int qtA = pair, qtB = 15 - pair;
  const int wqA = qtA * 128 + w * 32;
  const int wqB = qtB * 128 + w * 32;
  const int nt  = 2*qtB + 2;                  // block-uniform (qtB >= 8 > qtA)

  const char* Kgb = (const char*)(KVb + (size_t)b * S_LEN * 2048 + kvh * HDIM);
  const char* Vgb = (const char*)(Vt + (size_t)bk * HDIM * S_LEN);
  char* pb = L + 65536 + w*4096;

  const int krow_in = lane >> 4;
  const int kbyte   = l15 * 16;
  const int vrow_in = lane >> 3;
  const int vbyte   = (lane & 7) * 16;

  auto STAGE = [&](int kv0, int bf){
    char* kb = L + bf*32768;
    char* vb = kb + 16384;
    #pragma unroll
    for (int i = 0; i < 4; ++i){
      int c = w*4 + i;
      int krow = c*4 + krow_in;
      const char* ksrc = Kgb + (size_t)(kv0 + krow) * 4096 + (kbyte ^ ((krow & 7) << 4));
      __builtin_amdgcn_global_load_lds(
        (const __attribute__((address_space(1))) void*)ksrc,
        (__attribute__((address_space(3))) void*)(kb + c*1024), 16, 0, 0);
      int vrow = c*8 + vrow_in;
      const char* vsrc = Vgb + (size_t)vrow * (S_LEN*2) + kv0*2 + (vbyte ^ ((vrow & 7) << 4));
      __builtin_amdgcn_global_load_lds(
        (const __attribute__((address_space(1))) void*)vsrc,
        (__attribute__((address_space(3))) void*)(vb + c*1024), 16, 0, 0);
    }
  };

  // hoist Q fragments for both q-tiles
  s16x8 qfA[2][4], qfB[2][4];
  #pragma unroll
  for (int m = 0; m < 2; ++m){
    const ushort* qpA = Q + (size_t)(b*S_LEN + wqA + m*16 + l15) * (NHEAD*HDIM) + h*HDIM + l4*8;
    const ushort* qpB = Q + (size_t)(b*S_LEN + wqB + m*16 + l15) * (NHEAD*HDIM) + h*HDIM + l4*8;
    #pragma unroll
    for (int kk = 0; kk < 4; ++kk){
      qfA[m][kk] = *(const s16x8*)(qpA + kk*32);
      qfB[m][kk] = *(const s16x8*)(qpB + kk*32);
    }
  }

  float mA0 = -1e30f, mA1 = -1e30f, lA0 = 0.f, lA1 = 0.f;
  float mB0 = -1e30f, mB1 = -1e30f, lB0 = 0.f, lB1 = 0.f;
  f32x4 oA[2][8] = {}, oB[2][8] = {};

  // per-tile compute for one q-tile (statically inlined at 2 call sites)
  auto TILE = [&](int kv0, const char* kb, const char* vb, s16x8 (&qf)[2][4],
                  float& m0, float& m1, float& l0, float& l1,
                  f32x4 (&oacc)[2][8], int wq0){
    const int qlane0 = wq0 + l15, qlane1 = qlane0 + 16;
    f32x4 st[4][2] = {};
    #pragma unroll
    for (int kk = 0; kk < 4; ++kk){
      s16x8 kf[4];
      #pragma unroll
      for (int i = 0; i < 4; ++i){
        int row = i*16 + l15;
        kf[i] = *(const s16x8*)(kb + row*256 + ((kk*64 + l4*16) ^ swz));
      }
      __builtin_amdgcn_s_setprio(1);
      #pragma unroll
      for (int i = 0; i < 4; ++i){
        st[i][0] = __builtin_amdgcn_mfma_f32_16x16x32_bf16(kf[i], qf[0][kk], st[i][0], 0, 0, 0);
        st[i][1] = __builtin_amdgcn_mfma_f32_16x16x32_bf16(kf[i], qf[1][kk], st[i][1], 0, 0, 0);
      }
      __builtin_amdgcn_s_setprio(0);
    }
    if (kv0 + 63 > wq0){
      #pragma unroll
      for (int i = 0; i < 4; ++i){
        int kvb = kv0 + i*16 + l4*4;
        #pragma unroll
        for (int r = 0; r < 4; ++r){
          if (kvb + r > qlane0) st[i][0][r] = -1e30f;
          if (kvb + r > qlane1) st[i][1][r] = -1e30f;
        }
      }
    }
    float mx0 = -1e30f, mx1 = -1e30f;
    #pragma unroll
    for (int i = 0; i < 4; ++i){
      mx0 = fmaxf(mx0, fmaxf(fmaxf(st[i][0][0], st[i][0][1]), fmaxf(st[i][0][2], st[i][0][3])));
      mx1 = fmaxf(mx1, fmaxf(fmaxf(st[i][1][0], st[i][1][1]), fmaxf(st[i][1][2], st[i][1][3])));
    }
    mx0 = fmaxf(mx0, __shfl_xor(mx0, 16)); mx0 = fmaxf(mx0, __shfl_xor(mx0, 32));
    mx1 = fmaxf(mx1, __shfl_xor(mx1, 16)); mx1 = fmaxf(mx1, __shfl_xor(mx1, 32));
    bool resc = !__all((mx0 <= m0 + 8.0f) & (mx1 <= m1 + 8.0f));
    if (resc){
      float mn0 = fmaxf(m0, mx0), mn1 = fmaxf(m1, mx1);
      float fs0 = __expf(m0 - mn0), fs1 = __expf(m1 - mn1);
      m0 = mn0; m1 = mn1; l0 *= fs0; l1 *= fs1;
      #pragma unroll
      for (int m = 0; m < 2; ++m){
        float fsm = m ? fs1 : fs0;
        #pragma unroll
        for (int r = 0; r < 4; ++r){
          float fb = __shfl(fsm, (lane & 48) | (l4*4 + r));
          #pragma unroll
          for (int n = 0; n < 8; ++n) oacc[m][n][r] *= fb;
        }
      }
    }
    float s0 = 0.f, s1 = 0.f;
    #pragma unroll
    for (int i = 0; i < 4; ++i){
      int col2 = (i*16 + l4*4) * 2;
      f32x4 p0, p1;
      #pragma unroll
      for (int r = 0; r < 4; ++r){
        p0[r] = __expf(st[i][0][r] - m0); s0 += p0[r];
        p1[r] = __expf(st[i][1][r] - m1); s1 += p1[r];
      }
      s16x4 u0, u1;
      #pragma unroll
      for (int r = 0; r < 4; ++r){ u0[r] = (short)f2bf(p0[r]); u1[r] = (short)f2bf(p1[r]); }
      *(s16x4*)(pb + ((l15*128 + col2) ^ swz))        = u0;
      *(s16x4*)(pb + (((16 + l15)*128 + col2) ^ swz)) = u1;
    }
    l0 += s0; l1 += s1;
    #pragma unroll
    for (int kk = 0; kk < 2; ++kk){
      s16x8 pf0 = *(const s16x8*)(pb + ((l15*128 + kk*64 + l4*16) ^ swz));
      s16x8 pf1 = *(const s16x8*)(pb + (((16 + l15)*128 + kk*64 + l4*16) ^ swz));
      s16x8 vf[8];
      #pragma unroll
      for (int n = 0; n < 8; ++n){
        int row = n*16 + l15;
        vf[n] = *(const s16x8*)(vb + row*128 + ((kk*64 + l4*16) ^ swz));
      }
      __builtin_amdgcn_s_setprio(1);
      #pragma unroll
      for (int n = 0; n < 8; ++n){
        oacc[0][n] = __builtin_amdgcn_mfma_f32_16x16x32_bf16(pf0, vf[n], oacc[0][n], 0, 0, 0);
        oacc[1][n] = __builtin_amdgcn_mfma_f32_16x16x32_bf16(pf1, vf[n], oacc[1][n], 0, 0, 0);
      }
      __builtin_amdgcn_s_setprio(0);
    }
  };

  int cur = 0;
  STAGE(0, 0);
  __syncthreads();

  for (int t = 0; t < nt; ++t){
    const int kv0 = t * 64;
    if (t + 1 < nt) STAGE(kv0 + 64, cur ^ 1);
    const char* kb = L + cur*32768;
    const char* vb = kb + 16384;
    if (kv0 <= wqA + 31)
      TILE(kv0, kb, vb, qfA, mA0, mA1, lA0, lA1, oA, wqA);
    if (kv0 <= wqB + 31)
      TILE(kv0, kb, vb, qfB, mB0, mB1, lB0, lB1, oB, wqB);
    __syncthreads();
    cur ^= 1;
  }

  // ---- epilogues ----
  auto EPI = [&](float l0, float l1, f32x4 (&oacc)[2][8], int wq0){
    l0 += __shfl_xor(l0, 16); l0 += __shfl_xor(l0, 32);
    l1 += __shfl_xor(l1, 16); l1 += __shfl_xor(l1, 32);
    float inv0 = 1.0f / l0, inv1 = 1.0f / l1;
    #pragma unroll
    for (int m = 0; m < 2; ++m){
      float invm = m ? inv1 : inv0;
      #pragma unroll
      for (int r = 0; r < 4; ++r){
        float ib = __shfl(invm, (lane & 48) | (l4*4 + r));
        ushort* dst = AO + (size_t)(b*S_LEN + wq0 + m*16 + l4*4 + r) * (NHEAD*HDIM) + h*HDIM;
        #pragma unroll
        for (int n = 0; n < 8; ++n)
          dst[n*16 + l15] = f2bf(oacc[m][n][r] * ib);
      }
    }
  };
  EPI(lA0, lA1, oA, wqA);
  EPI(lB0, lB1, oB, wqB);
}

extern "C" void kernel_launch(void* const* d_in, const int* in_sizes, int n_in,
                              void* d_out, int out_size, void* d_ws, size_t ws_size,
                              hipStream_t stream)
{
  const float* X  = (const float*)d_in[0];
  const float* Wq = (const float*)d_in[3];
  const float* Wk = (const float*)d_in[4];
  const float* Wv = (const float*)d_in[5];
  const float* Wo = (const float*)d_in[6];

  char* ws = (char*)d_ws;
  float*  cost = (float*) (ws + 0);           // 512 KB
  float*  sint = (float*) (ws + 524288);      // 512 KB
  ushort* Xb   = (ushort*)(ws + 1048576);     // 33.5 MB
  ushort* WqT  = (ushort*)(ws + 34603008);    // 33.5 MB
  ushort* WkvT = (ushort*)(ws + 68157440);    // 16.8 MB  [2048][4096]
  ushort* Qb   = (ushort*)(ws + 84934656);    // 33.5 MB
  ushort* KVb  = (ushort*)(ws + 118489088);   // 16.8 MB  [4096][2048] (K cols 0..1023 used)
  ushort* Vt   = (ushort*)(ws + 135266304);   // 8.4 MB
  ushort* WoT  = (ushort*)(ws + 143654912);   // 33.5 MB  (end 177209344)
  ushort* AO   = WqT;                         // WqT dead after Q GEMM

  const float qk_scale = 0.08838834764831845f;  // 1/sqrt(128), folded into Q RoPE

  const int GLDS = 131072;
  const int ALDS = 81920;
  hipFuncSetAttribute((const void*)gemm256<1>, hipFuncAttributeMaxDynamicSharedMemorySize, GLDS);
  hipFuncSetAttribute((const void*)gemm256<2>, hipFuncAttributeMaxDynamicSharedMemorySize, GLDS);
  hipFuncSetAttribute((const void*)attn_k,     hipFuncAttributeMaxDynamicSharedMemorySize, ALDS);

  prep_k<<<dim3(64, 288), 256, 0, stream>>>(Wq, Wk, Wv, Wo, WqT, WkvT, WoT, X, Xb, cost, sint);

  gemm256<1><<<256, 512, GLDS, stream>>>(Xb, WqT, Qb, 4096, 4096, 4096, cost, sint, qk_scale);
  gemm_bt<3><<<dim3(32, 16), 256, 0, stream>>>(Xb, WkvT, KVb, 4096, 2048, 4096, cost, sint, 1.0f, Vt);

  attn_k<<<512, 256, ALDS, stream>>>(Qb, KVb, Vt, AO);

  gemm256<2><<<256, 512, GLDS, stream>>>(AO, WoT, d_out, 4096, 4096, 4096, nullptr, nullptr, 1.0f);
}

// Round 17
// 468.185 us; speedup vs baseline: 1.3417x; 1.3417x over previous
//
#include <hip/hip_runtime.h>
#include <hip/hip_bf16.h>
#include <stdint.h>
#include <math.h>

#define S_LEN 2048
#define NHEAD 32
#define NKVH  8
#define HDIM  128
#define HID   4096

typedef __attribute__((ext_vector_type(4))) float f32x4;
typedef __attribute__((ext_vector_type(8))) short s16x8;
typedef __attribute__((ext_vector_type(4))) short s16x4;

__device__ __forceinline__ float bf2f(ushort u){
  union { float f; uint32_t i; } c; c.i = ((uint32_t)u) << 16; return c.f;
}
__device__ __forceinline__ ushort f2bf(float f){
  union { float f; uint32_t i; } c; c.f = f;
  uint32_t i = c.i;
  return (ushort)((i + 0x7FFFu + ((i >> 16) & 1u)) >> 16);
}

// ---------------- weight transpose-convert body: W f32[K,N] -> WT bf16[N,K] ----------------
__device__ __forceinline__ void wtrans_body(const float* __restrict__ W, ushort* __restrict__ WT,
                                            int K, int N, int k0, int n0, int tid){
  __shared__ float T[64][68];
  #pragma unroll
  for (int it = 0; it < 4; ++it){
    int slot = it*256 + tid;
    int kr = slot >> 4, c4 = slot & 15;
    f32x4 v = *(const f32x4*)(W + (size_t)(k0 + kr) * N + n0 + c4*4);
    *(f32x4*)&T[kr][c4*4] = v;
  }
  __syncthreads();
  #pragma unroll
  for (int it = 0; it < 2; ++it){
    int slot = it*256 + tid;
    int nr = slot >> 3, k8 = slot & 7;
    s16x8 o;
    #pragma unroll
    for (int j = 0; j < 8; ++j) o[j] = f2bf(T[k8*8 + j][nr]);
    *(s16x8*)(WT + (size_t)(n0 + nr) * K + k0 + k8*8) = o;
  }
}

// fused prep: y<64 Wq, 64..79 Wk, 80..95 Wv, 96..159 Wo transpose; y>=160: X cvt + RoPE table
__global__ void prep_k(const float* __restrict__ Wq, const float* __restrict__ Wk,
                       const float* __restrict__ Wv, const float* __restrict__ Wo,
                       ushort* __restrict__ WqT, ushort* __restrict__ WkvT,
                       ushort* __restrict__ WoT,
                       const float* __restrict__ X, ushort* __restrict__ Xb,
                       float* __restrict__ cost, float* __restrict__ sint){
  int y = blockIdx.y;
  if (y < 160){
    const float* W; ushort* WT; int N, n0;
    if (y < 64){ W = Wq; WT = WqT;  N = 4096; n0 = y*64; }
    else if (y < 80){ W = Wk; WT = WkvT; N = 1024; n0 = (y-64)*64; }
    else if (y < 96){ W = Wv; WT = WkvT + (size_t)1024*HID; N = 1024; n0 = (y-80)*64; }
    else { W = Wo; WT = WoT; N = 4096; n0 = (y-96)*64; }
    wtrans_body(W, WT, HID, N, blockIdx.x*64, n0, threadIdx.x);
  } else {
    int cid = (y - 160) * 64 + blockIdx.x;    // 0..8191
    int ri = cid * 256 + threadIdx.x;
    if (ri < S_LEN * 64){
      int s = ri >> 6, j = ri & 63;
      float invf = powf(10000.0f, -(float)j * (1.0f / 64.0f));
      float a = (float)s * invf;
      cost[ri] = cosf(a);
      sint[ri] = sinf(a);
    }
    size_t i = ((size_t)cid * 256 + threadIdx.x) * 8;
    f32x4 a = *(const f32x4*)(X + i);
    f32x4 b = *(const f32x4*)(X + i + 4);
    s16x8 o;
    o[0]=f2bf(a[0]); o[1]=f2bf(a[1]); o[2]=f2bf(a[2]); o[3]=f2bf(a[3]);
    o[4]=f2bf(b[0]); o[5]=f2bf(b[1]); o[6]=f2bf(b[2]); o[7]=f2bf(b[3]);
    *(s16x8*)(Xb + i) = o;
  }
}

// ---------------- 128x128 GEMM, T2 swizzle + double-buffered 2-phase (T3 minimum) ----------------
// EPI: 0 = bf16 out, 2 = f32 out,
// EPI 3 = KV projection: cols < 1024 -> RoPE'd K into KVb; cols >= 1024 -> V packed into Vt
template<int EPI>
__global__ __launch_bounds__(256)
void gemm_bt(const ushort* __restrict__ A, const ushort* __restrict__ Bt,
             void* __restrict__ Cout, int M, int N, int K,
             const float* __restrict__ cost, const float* __restrict__ sint,
             float oscale, ushort* __restrict__ Vt)
{
  __shared__ ushort As[2][128*64];
  __shared__ ushort Bs[2][128*64];
  const int tid = threadIdx.x;
  const int w = tid >> 6, lane = tid & 63;
  const int l15 = lane & 15, l4 = lane >> 4;
  const int swz = (l15 & 7) << 4;
  const size_t Abase = (size_t)blockIdx.x * 128 * K;
  const size_t Bbase = (size_t)blockIdx.y * 128 * K;

  f32x4 acc[2][8] = {};

  const int srow = (w << 3) + (lane >> 3);
  const int scolb = ((lane & 7) * 16) ^ (((lane >> 3) & 7) << 4);
  const ushort* Agrow = A + Abase + (size_t)srow * K;
  const ushort* Bgrow = Bt + Bbase + (size_t)srow * K;

  auto STAGE = [&](int bf, int k0){
    #pragma unroll
    for (int i = 0; i < 4; ++i){
      __builtin_amdgcn_global_load_lds(
        (const __attribute__((address_space(1))) void*)((const char*)(Agrow + k0 + (size_t)(32*i)*K) + scolb),
        (__attribute__((address_space(3))) void*)((char*)As[bf] + w*1024 + i*4096), 16, 0, 0);
      __builtin_amdgcn_global_load_lds(
        (const __attribute__((address_space(1))) void*)((const char*)(Bgrow + k0 + (size_t)(32*i)*K) + scolb),
        (__attribute__((address_space(3))) void*)((char*)Bs[bf] + w*1024 + i*4096), 16, 0, 0);
    }
  };

  const int nt = K >> 6;
  int cur = 0;
  STAGE(0, 0);
  __syncthreads();

  for (int t = 0; t < nt; ++t){
    if (t + 1 < nt) STAGE(cur ^ 1, (t + 1) * 64);
    #pragma unroll
    for (int kk = 0; kk < 2; ++kk){
      s16x8 af[2], bfr[8];
      #pragma unroll
      for (int m = 0; m < 2; ++m)
        af[m] = *(const s16x8*)((char*)As[cur] + (w*32 + m*16 + l15)*128 + ((kk*64 + l4*16) ^ swz));
      #pragma unroll
      for (int n = 0; n < 8; ++n)
        bfr[n] = *(const s16x8*)((char*)Bs[cur] + (n*16 + l15)*128 + ((kk*64 + l4*16) ^ swz));
      __builtin_amdgcn_s_setprio(1);
      #pragma unroll
      for (int m = 0; m < 2; ++m)
        #pragma unroll
        for (int n = 0; n < 8; ++n)
          acc[m][n] = __builtin_amdgcn_mfma_f32_16x16x32_bf16(af[m], bfr[n], acc[m][n], 0, 0, 0);
      __builtin_amdgcn_s_setprio(0);
    }
    __syncthreads();
    cur ^= 1;
  }

  const int r0 = (int)blockIdx.x * 128 + w * 32;
  const int c0 = (int)blockIdx.y * 128;
  if (EPI == 2){
    float* C = (float*)Cout;
    #pragma unroll
    for (int m = 0; m < 2; ++m)
      #pragma unroll
      for (int r = 0; r < 4; ++r){
        size_t rowoff = (size_t)(r0 + m*16 + l4*4 + r) * N + c0;
        #pragma unroll
        for (int n = 0; n < 8; ++n)
          C[rowoff + n*16 + l15] = acc[m][n][r];
      }
  } else if (EPI == 0){
    ushort* C = (ushort*)Cout;
    #pragma unroll
    for (int m = 0; m < 2; ++m)
      #pragma unroll
      for (int r = 0; r < 4; ++r){
        size_t rowoff = (size_t)(r0 + m*16 + l4*4 + r) * N + c0;
        #pragma unroll
        for (int n = 0; n < 8; ++n)
          C[rowoff + n*16 + l15] = f2bf(acc[m][n][r]);
      }
  } else if (EPI == 3 && c0 >= 1024){
    const int kvh = (c0 - 1024) >> 7;
    #pragma unroll
    for (int m = 0; m < 2; ++m){
      int row0 = r0 + m*16 + l4*4;
      int b = row0 >> 11, s = row0 & (S_LEN - 1);
      ushort* vbase = Vt + ((size_t)(b*NKVH + kvh) * HDIM) * S_LEN + s;
      #pragma unroll
      for (int n = 0; n < 8; ++n){
        s16x4 pk;
        #pragma unroll
        for (int r = 0; r < 4; ++r) pk[r] = (short)f2bf(acc[m][n][r]);
        *(s16x4*)(vbase + (size_t)(n*16 + l15) * S_LEN) = pk;
      }
    }
  } else {
    ushort* C = (ushort*)Cout;
    #pragma unroll
    for (int m = 0; m < 2; ++m)
      #pragma unroll
      for (int r = 0; r < 4; ++r){
        int row = r0 + m*16 + l4*4 + r;
        int pos = row & (S_LEN - 1);
        size_t rowoff = (size_t)row * N + c0;
        #pragma unroll
        for (int n = 0; n < 4; ++n){
          int d = n*16 + l15;
          float cv = cost[pos*64 + d];
          float sv = sint[pos*64 + d];
          float x1 = acc[m][n][r];
          float x2 = acc[m][n+4][r];
          C[rowoff + d]      = f2bf((x1*cv - x2*sv) * oscale);
          C[rowoff + d + 64] = f2bf((x2*cv + x1*sv) * oscale);
        }
      }
  }
}

// ---------------- 256x256 8-phase GEMM (T2+T3+T4+T5), depth-3 prefetch, 1 barrier/phase ----------------
template<int EPI>
__global__ __launch_bounds__(512, 2)
void gemm256(const ushort* __restrict__ A, const ushort* __restrict__ Bt,
             void* __restrict__ Cout, int M, int N, int K,
             const float* __restrict__ cost, const float* __restrict__ sint,
             float oscale)
{
  extern __shared__ char L[];                 // 131072 B
  const int tid = threadIdx.x;
  const int wid = tid >> 6, lane = tid & 63;
  const int wm = wid >> 2, wn = wid & 3;
  const int l15 = lane & 15, l4 = lane >> 4;
  const int swz = (l15 & 7) << 4;
  const int nwg  = gridDim.x;
  const int bid  = blockIdx.x;
  const int sbid = (bid & 7) * (nwg >> 3) + (bid >> 3);
  const int gx   = sbid & 15, gy = sbid >> 4;
  const int brow = gx * 256, bcol = gy * 256;
  const int nt = K >> 6;

  f32x4 acc[8][4] = {};
  s16x8 areg[8], b0reg[4], b1reg[4];

  auto STAGE = [&](int arr, int sh, int bf, int tile){
    int tt = tile < nt ? tile : nt - 1;
    const ushort* gb = arr ? (Bt + (size_t)bcol * K) : (A + (size_t)brow * K);
    char* lb = L + bf*65536 + arr*32768;
    #pragma unroll
    for (int j = 0; j < 2; ++j){
      int c   = j*8 + wid;
      int rg0 = (c >= 8 ? 128 : 0) + sh*64 + ((c*8) & 63);
      int rg  = rg0 + (lane >> 3);
      const char* gsrc = (const char*)(gb + (size_t)rg * K + tt*64)
                       + (((lane & 7) * 16) ^ (((lane >> 3) & 7) << 4));
      __builtin_amdgcn_global_load_lds(
        (const __attribute__((address_space(1))) void*)gsrc,
        (__attribute__((address_space(3))) void*)(lb + rg0*128), 16, 0, 0);
    }
  };
  auto LDA = [&](int bf, int mh){
    const char* ab = L + bf*65536;
    #pragma unroll
    for (int i = 0; i < 4; ++i){
      int row = wm*128 + (mh*4 + i)*16 + l15;
      #pragma unroll
      for (int kk = 0; kk < 2; ++kk)
        areg[i*2+kk] = *(const s16x8*)(ab + row*128 + ((kk*64 + l4*16) ^ swz));
    }
  };
  auto LDB = [&](int bf, int nh, s16x8* breg){
    const char* bb = L + bf*65536 + 32768;
    #pragma unroll
    for (int j = 0; j < 2; ++j){
      int row = wn*64 + (nh*2 + j)*16 + l15;
      #pragma unroll
      for (int kk = 0; kk < 2; ++kk)
        breg[j*2+kk] = *(const s16x8*)(bb + row*128 + ((kk*64 + l4*16) ^ swz));
    }
  };
  auto MFMA16 = [&](int mh, int nh, s16x8* breg){
    __builtin_amdgcn_s_setprio(1);
    #pragma unroll
    for (int kk = 0; kk < 2; ++kk)
      #pragma unroll
      for (int i = 0; i < 4; ++i)
        #pragma unroll
        for (int j = 0; j < 2; ++j)
          acc[mh*4+i][nh*2+j] = __builtin_amdgcn_mfma_f32_16x16x32_bf16(
              areg[i*2+kk], breg[j*2+kk], acc[mh*4+i][nh*2+j], 0, 0, 0);
    __builtin_amdgcn_s_setprio(0);
  };

  STAGE(0,0,0,0); STAGE(1,0,0,0); STAGE(0,1,0,0); STAGE(1,1,0,0);
  STAGE(0,0,1,1); STAGE(1,0,1,1); STAGE(0,1,1,1);
  asm volatile("s_waitcnt vmcnt(6)" ::: "memory");
  __builtin_amdgcn_s_barrier();

  for (int t = 0; t < nt; t += 2){
    LDA(0,0); LDB(0,0,b0reg); STAGE(1,1,1,t+1);
    __builtin_amdgcn_s_barrier();
    MFMA16(0,0,b0reg);
    LDB(0,1,b1reg); STAGE(0,0,0,t+2);
    __builtin_amdgcn_s_barrier();
    MFMA16(0,1,b1reg);
    LDA(0,1); STAGE(1,0,0,t+2);
    __builtin_amdgcn_s_barrier();
    MFMA16(1,0,b0reg);
    STAGE(0,1,0,t+2);
    asm volatile("s_waitcnt vmcnt(6)" ::: "memory");
    __builtin_amdgcn_s_barrier();
    MFMA16(1,1,b1reg);
    LDA(1,0); LDB(1,0,b0reg); STAGE(1,1,0,t+2);
    __builtin_amdgcn_s_barrier();
    MFMA16(0,0,b0reg);
    LDB(1,1,b1reg); STAGE(0,0,1,t+3);
    __builtin_amdgcn_s_barrier();
    MFMA16(0,1,b1reg);
    LDA(1,1); STAGE(1,0,1,t+3);
    __builtin_amdgcn_s_barrier();
    MFMA16(1,0,b0reg);
    STAGE(0,1,1,t+3);
    asm volatile("s_waitcnt vmcnt(6)" ::: "memory");
    __builtin_amdgcn_s_barrier();
    MFMA16(1,1,b1reg);
  }
  asm volatile("s_waitcnt vmcnt(0)" ::: "memory");
  __builtin_amdgcn_s_barrier();

  if (EPI == 2){
    float* C = (float*)Cout;
    #pragma unroll
    for (int m = 0; m < 8; ++m)
      #pragma unroll
      for (int r = 0; r < 4; ++r){
        size_t rowoff = (size_t)(brow + wm*128 + m*16 + l4*4 + r) * N + bcol + wn*64;
        #pragma unroll
        for (int n = 0; n < 4; ++n)
          C[rowoff + n*16 + l15] = acc[m][n][r];
      }
  } else {
    float* xls = (float*)L;
    ushort* C = (ushort*)Cout;
    float* mine = xls + wid*2176;
    const float* part = xls + (wid^1)*2176;
    #pragma unroll
    for (int mm = 0; mm < 4; ++mm){
      #pragma unroll
      for (int mi = 0; mi < 2; ++mi){
        int m = mm*2 + mi;
        #pragma unroll
        for (int r = 0; r < 4; ++r)
          #pragma unroll
          for (int n = 0; n < 4; ++n)
            mine[(mi*16 + l4*4 + r)*68 + n*16 + l15] = acc[m][n][r];
      }
      __builtin_amdgcn_s_barrier();
      #pragma unroll
      for (int mi = 0; mi < 2; ++mi){
        int m = mm*2 + mi;
        #pragma unroll
        for (int r = 0; r < 4; ++r){
          int rr = brow + wm*128 + m*16 + l4*4 + r;
          int pos = rr & (S_LEN - 1);
          size_t rowoff = (size_t)rr * N + bcol + wn*64;
          #pragma unroll
          for (int n = 0; n < 4; ++n){
            int d2 = n*16 + l15;
            float x  = acc[m][n][r];
            float px = part[(mi*16 + l4*4 + r)*68 + d2];
            float cv = cost[pos*64 + d2], sv = sint[pos*64 + d2];
            float o = (wn & 1) ? (x*cv + px*sv) : (x*cv - px*sv);
            C[rowoff + d2] = f2bf(o * oscale);
          }
        }
      }
      __builtin_amdgcn_s_barrier();
    }
  }
}

// ---------------- causal GQA flash attention, LDS-staged double-buffered (two-pass) ----------------
__global__ __launch_bounds__(256, 2)
void attn_k(const ushort* __restrict__ Q, const ushort* __restrict__ KVb,
            const ushort* __restrict__ Vt, ushort* __restrict__ AO)
{
  extern __shared__ char L[];
  const int tid = threadIdx.x, w = tid >> 6, lane = tid & 63;
  const int l15 = lane & 15, l4 = lane >> 4;
  const int swz = (l15 & 7) << 4;

  const int id  = blockIdx.x;
  const int idx = id >> 3;
  const int bk  = (id & 7) * 2 + (idx & 1);   // b*8 + kvh
  const int b   = bk >> 3, kvh = bk & 7;
  const int h   = kvh * 4 + ((idx >> 1) & 3);
  const int pair= idx >> 3;                   // 0..7 -> q-tiles {pair, 15-pair}

  const char* Kgb = (const char*)(KVb + (size_t)b * S_LEN * 2048 + kvh * HDIM);
  const char* Vgb = (const char*)(Vt + (size_t)bk * HDIM * S_LEN);
  char* pb = L + 65536 + w*4096;

  const int krow_in = lane >> 4;
  const int kbyte   = l15 * 16;
  const int vrow_in = lane >> 3;
  const int vbyte   = (lane & 7) * 16;

  auto STAGE = [&](int kv0, int bf){
    char* kb = L + bf*32768;
    char* vb = kb + 16384;
    #pragma unroll
    for (int i = 0; i < 4; ++i){
      int c = w*4 + i;
      int krow = c*4 + krow_in;
      const char* ksrc = Kgb + (size_t)(kv0 + krow) * 4096 + (kbyte ^ ((krow & 7) << 4));
      __builtin_amdgcn_global_load_lds(
        (const __attribute__((address_space(1))) void*)ksrc,
        (__attribute__((address_space(3))) void*)(kb + c*1024), 16, 0, 0);
      int vrow = c*8 + vrow_in;
      const char* vsrc = Vgb + (size_t)vrow * (S_LEN*2) + kv0*2 + (vbyte ^ ((vrow & 7) << 4));
      __builtin_amdgcn_global_load_lds(
        (const __attribute__((address_space(1))) void*)vsrc,
        (__attribute__((address_space(3))) void*)(vb + c*1024), 16, 0, 0);
    }
  };

  #pragma unroll
  for (int half = 0; half < 2; ++half){
    const int qt  = half ? (15 - pair) : pair;
    const int wq0 = qt * 128 + w * 32;
    const int nt  = 2*qt + 2;

    s16x8 qf[2][4];
    #pragma unroll
    for (int m = 0; m < 2; ++m){
      const ushort* qp = Q + (size_t)(b*S_LEN + wq0 + m*16 + l15) * (NHEAD*HDIM) + h*HDIM + l4*8;
      #pragma unroll
      for (int kk = 0; kk < 4; ++kk)
        qf[m][kk] = *(const s16x8*)(qp + kk*32);
    }

    float mreg0 = -1e30f, mreg1 = -1e30f, lreg0 = 0.f, lreg1 = 0.f;
    f32x4 oacc[2][8] = {};
    const int qlane0 = wq0 + l15, qlane1 = qlane0 + 16;

    int cur = 0;
    STAGE(0, 0);
    __syncthreads();

    for (int t = 0; t < nt; ++t){
      const int kv0 = t * 64;
      if (t + 1 < nt) STAGE(kv0 + 64, cur ^ 1);
      if (kv0 <= wq0 + 31){
        const char* kb = L + cur*32768;
        const char* vb = kb + 16384;
        f32x4 st[4][2] = {};
        #pragma unroll
        for (int kk = 0; kk < 4; ++kk){
          s16x8 kf[4];
          #pragma unroll
          for (int i = 0; i < 4; ++i){
            int row = i*16 + l15;
            kf[i] = *(const s16x8*)(kb + row*256 + ((kk*64 + l4*16) ^ swz));
          }
          __builtin_amdgcn_s_setprio(1);
          #pragma unroll
          for (int i = 0; i < 4; ++i){
            st[i][0] = __builtin_amdgcn_mfma_f32_16x16x32_bf16(kf[i], qf[0][kk], st[i][0], 0, 0, 0);
            st[i][1] = __builtin_amdgcn_mfma_f32_16x16x32_bf16(kf[i], qf[1][kk], st[i][1], 0, 0, 0);
          }
          __builtin_amdgcn_s_setprio(0);
        }
        if (kv0 + 63 > wq0){
          #pragma unroll
          for (int i = 0; i < 4; ++i){
            int kvb = kv0 + i*16 + l4*4;
            #pragma unroll
            for (int r = 0; r < 4; ++r){
              if (kvb + r > qlane0) st[i][0][r] = -1e30f;
              if (kvb + r > qlane1) st[i][1][r] = -1e30f;
            }
          }
        }
        float mx0 = -1e30f, mx1 = -1e30f;
        #pragma unroll
        for (int i = 0; i < 4; ++i){
          mx0 = fmaxf(mx0, fmaxf(fmaxf(st[i][0][0], st[i][0][1]), fmaxf(st[i][0][2], st[i][0][3])));
          mx1 = fmaxf(mx1, fmaxf(fmaxf(st[i][1][0], st[i][1][1]), fmaxf(st[i][1][2], st[i][1][3])));
        }
        mx0 = fmaxf(mx0, __shfl_xor(mx0, 16)); mx0 = fmaxf(mx0, __shfl_xor(mx0, 32));
        mx1 = fmaxf(mx1, __shfl_xor(mx1, 16)); mx1 = fmaxf(mx1, __shfl_xor(mx1, 32));
        bool resc = !__all((mx0 <= mreg0 + 8.0f) & (mx1 <= mreg1 + 8.0f));
        if (resc){
          float mn0 = fmaxf(mreg0, mx0), mn1 = fmaxf(mreg1, mx1);
          float fs0 = __expf(mreg0 - mn0), fs1 = __expf(mreg1 - mn1);
          mreg0 = mn0; mreg1 = mn1; lreg0 *= fs0; lreg1 *= fs1;
          #pragma unroll
          for (int m = 0; m < 2; ++m){
            float fsm = m ? fs1 : fs0;
            #pragma unroll
            for (int r = 0; r < 4; ++r){
              float fb = __shfl(fsm, (lane & 48) | (l4*4 + r));
              #pragma unroll
              for (int n = 0; n < 8; ++n) oacc[m][n][r] *= fb;
            }
          }
        }
        float s0 = 0.f, s1 = 0.f;
        #pragma unroll
        for (int i = 0; i < 4; ++i){
          int col2 = (i*16 + l4*4) * 2;
          f32x4 p0, p1;
          #pragma unroll
          for (int r = 0; r < 4; ++r){
            p0[r] = __expf(st[i][0][r] - mreg0); s0 += p0[r];
            p1[r] = __expf(st[i][1][r] - mreg1); s1 += p1[r];
          }
          s16x4 u0, u1;
          #pragma unroll
          for (int r = 0; r < 4; ++r){ u0[r] = (short)f2bf(p0[r]); u1[r] = (short)f2bf(p1[r]); }
          *(s16x4*)(pb + ((l15*128 + col2) ^ swz))        = u0;
          *(s16x4*)(pb + (((16 + l15)*128 + col2) ^ swz)) = u1;
        }
        lreg0 += s0; lreg1 += s1;
        #pragma unroll
        for (int kk = 0; kk < 2; ++kk){
          s16x8 pf0 = *(const s16x8*)(pb + ((l15*128 + kk*64 + l4*16) ^ swz));
          s16x8 pf1 = *(const s16x8*)(pb + (((16 + l15)*128 + kk*64 + l4*16) ^ swz));
          s16x8 vf[8];
          #pragma unroll
          for (int n = 0; n < 8; ++n){
            int row = n*16 + l15;
            vf[n] = *(const s16x8*)(vb + row*128 + ((kk*64 + l4*16) ^ swz));
          }
          __builtin_amdgcn_s_setprio(1);
          #pragma unroll
          for (int n = 0; n < 8; ++n){
            oacc[0][n] = __builtin_amdgcn_mfma_f32_16x16x32_bf16(pf0, vf[n], oacc[0][n], 0, 0, 0);
            oacc[1][n] = __builtin_amdgcn_mfma_f32_16x16x32_bf16(pf1, vf[n], oacc[1][n], 0, 0, 0);
          }
          __builtin_amdgcn_s_setprio(0);
        }
      }
      __syncthreads();
      cur ^= 1;
    }

    lreg0 += __shfl_xor(lreg0, 16); lreg0 += __shfl_xor(lreg0, 32);
    lreg1 += __shfl_xor(lreg1, 16); lreg1 += __shfl_xor(lreg1, 32);
    float inv0 = 1.0f / lreg0, inv1 = 1.0f / lreg1;
    #pragma unroll
    for (int m = 0; m < 2; ++m){
      float invm = m ? inv1 : inv0;
      #pragma unroll
      for (int r = 0; r < 4; ++r){
        float ib = __shfl(invm, (lane & 48) | (l4*4 + r));
        ushort* dst = AO + (size_t)(b*S_LEN + wq0 + m*16 + l4*4 + r) * (NHEAD*HDIM) + h*HDIM;
        #pragma unroll
        for (int n = 0; n < 8; ++n)
          dst[n*16 + l15] = f2bf(oacc[m][n][r] * ib);
      }
    }
  }
}

extern "C" void kernel_launch(void* const* d_in, const int* in_sizes, int n_in,
                              void* d_out, int out_size, void* d_ws, size_t ws_size,
                              hipStream_t stream)
{
  const float* X  = (const float*)d_in[0];
  const float* Wq = (const float*)d_in[3];
  const float* Wk = (const float*)d_in[4];
  const float* Wv = (const float*)d_in[5];
  const float* Wo = (const float*)d_in[6];

  char* ws = (char*)d_ws;
  float*  cost = (float*) (ws + 0);           // 512 KB
  float*  sint = (float*) (ws + 524288);      // 512 KB
  ushort* Xb   = (ushort*)(ws + 1048576);     // 33.5 MB
  ushort* WqT  = (ushort*)(ws + 34603008);    // 33.5 MB
  ushort* WkvT = (ushort*)(ws + 68157440);    // 16.8 MB  [2048][4096]
  ushort* Qb   = (ushort*)(ws + 84934656);    // 33.5 MB
  ushort* KVb  = (ushort*)(ws + 118489088);   // 16.8 MB  [4096][2048] (K cols 0..1023 used)
  ushort* Vt   = (ushort*)(ws + 135266304);   // 8.4 MB
  ushort* WoT  = (ushort*)(ws + 143654912);   // 33.5 MB  (end 177209344)
  ushort* AO   = WqT;                         // WqT dead after Q GEMM

  const float qk_scale = 0.08838834764831845f;  // 1/sqrt(128), folded into Q RoPE

  const int GLDS = 131072;
  const int ALDS = 81920;
  hipFuncSetAttribute((const void*)gemm256<1>, hipFuncAttributeMaxDynamicSharedMemorySize, GLDS);
  hipFuncSetAttribute((const void*)gemm256<2>, hipFuncAttributeMaxDynamicSharedMemorySize, GLDS);
  hipFuncSetAttribute((const void*)attn_k,     hipFuncAttributeMaxDynamicSharedMemorySize, ALDS);

  prep_k<<<dim3(64, 288), 256, 0, stream>>>(Wq, Wk, Wv, Wo, WqT, WkvT, WoT, X, Xb, cost, sint);

  gemm256<1><<<256, 512, GLDS, stream>>>(Xb, WqT, Qb, 4096, 4096, 4096, cost, sint, qk_scale);
  gemm_bt<3><<<dim3(32, 16), 256, 0, stream>>>(Xb, WkvT, KVb, 4096, 2048, 4096, cost, sint, 1.0f, Vt);

  attn_k<<<512, 256, ALDS, stream>>>(Qb, KVb, Vt, AO);

  gemm256<2><<<256, 512, GLDS, stream>>>(AO, WoT, d_out, 4096, 4096, 4096, nullptr, nullptr, 1.0f);
}

// Round 18
// 464.046 us; speedup vs baseline: 1.3537x; 1.0089x over previous
//
#include <hip/hip_runtime.h>
#include <hip/hip_bf16.h>
#include <stdint.h>
#include <math.h>

#define S_LEN 2048
#define NHEAD 32
#define NKVH  8
#define HDIM  128
#define HID   4096

typedef __attribute__((ext_vector_type(4))) float f32x4;
typedef __attribute__((ext_vector_type(8))) short s16x8;
typedef __attribute__((ext_vector_type(4))) short s16x4;

__device__ __forceinline__ float bf2f(ushort u){
  union { float f; uint32_t i; } c; c.i = ((uint32_t)u) << 16; return c.f;
}
__device__ __forceinline__ ushort f2bf(float f){
  union { float f; uint32_t i; } c; c.f = f;
  uint32_t i = c.i;
  return (ushort)((i + 0x7FFFu + ((i >> 16) & 1u)) >> 16);
}

// ---------------- weight transpose-convert body: W f32[K,N] -> WT bf16[N,K] ----------------
__device__ __forceinline__ void wtrans_body(const float* __restrict__ W, ushort* __restrict__ WT,
                                            int K, int N, int k0, int n0, int tid){
  __shared__ float T[64][68];
  #pragma unroll
  for (int it = 0; it < 4; ++it){
    int slot = it*256 + tid;
    int kr = slot >> 4, c4 = slot & 15;
    f32x4 v = *(const f32x4*)(W + (size_t)(k0 + kr) * N + n0 + c4*4);
    *(f32x4*)&T[kr][c4*4] = v;
  }
  __syncthreads();
  #pragma unroll
  for (int it = 0; it < 2; ++it){
    int slot = it*256 + tid;
    int nr = slot >> 3, k8 = slot & 7;
    s16x8 o;
    #pragma unroll
    for (int j = 0; j < 8; ++j) o[j] = f2bf(T[k8*8 + j][nr]);
    *(s16x8*)(WT + (size_t)(n0 + nr) * K + k0 + k8*8) = o;
  }
}

// fused prep: y<64 Wq, 64..79 Wk, 80..95 Wv, 96..159 Wo transpose; y>=160: X cvt + RoPE table
__global__ void prep_k(const float* __restrict__ Wq, const float* __restrict__ Wk,
                       const float* __restrict__ Wv, const float* __restrict__ Wo,
                       ushort* __restrict__ WqT, ushort* __restrict__ WkvT,
                       ushort* __restrict__ WoT,
                       const float* __restrict__ X, ushort* __restrict__ Xb,
                       float* __restrict__ cost, float* __restrict__ sint){
  int y = blockIdx.y;
  if (y < 160){
    const float* W; ushort* WT; int N, n0;
    if (y < 64){ W = Wq; WT = WqT;  N = 4096; n0 = y*64; }
    else if (y < 80){ W = Wk; WT = WkvT; N = 1024; n0 = (y-64)*64; }
    else if (y < 96){ W = Wv; WT = WkvT + (size_t)1024*HID; N = 1024; n0 = (y-80)*64; }
    else { W = Wo; WT = WoT; N = 4096; n0 = (y-96)*64; }
    wtrans_body(W, WT, HID, N, blockIdx.x*64, n0, threadIdx.x);
  } else {
    int cid = (y - 160) * 64 + blockIdx.x;    // 0..8191
    int ri = cid * 256 + threadIdx.x;
    if (ri < S_LEN * 64){
      int s = ri >> 6, j = ri & 63;
      float invf = powf(10000.0f, -(float)j * (1.0f / 64.0f));
      float a = (float)s * invf;
      cost[ri] = cosf(a);
      sint[ri] = sinf(a);
    }
    size_t i = ((size_t)cid * 256 + threadIdx.x) * 8;
    f32x4 a = *(const f32x4*)(X + i);
    f32x4 b = *(const f32x4*)(X + i + 4);
    s16x8 o;
    o[0]=f2bf(a[0]); o[1]=f2bf(a[1]); o[2]=f2bf(a[2]); o[3]=f2bf(a[3]);
    o[4]=f2bf(b[0]); o[5]=f2bf(b[1]); o[6]=f2bf(b[2]); o[7]=f2bf(b[3]);
    *(s16x8*)(Xb + i) = o;
  }
}

// ---------------- 128x128 GEMM, T2 swizzle + double-buffered 2-phase (T3 minimum) ----------------
// EPI: 0 = bf16 out, 2 = f32 out,
// EPI 3 = KV projection: cols < 1024 -> RoPE'd K into KVb; cols >= 1024 -> V packed into Vt
template<int EPI>
__global__ __launch_bounds__(256)
void gemm_bt(const ushort* __restrict__ A, const ushort* __restrict__ Bt,
             void* __restrict__ Cout, int M, int N, int K,
             const float* __restrict__ cost, const float* __restrict__ sint,
             float oscale, ushort* __restrict__ Vt)
{
  __shared__ ushort As[2][128*64];
  __shared__ ushort Bs[2][128*64];
  const int tid = threadIdx.x;
  const int w = tid >> 6, lane = tid & 63;
  const int l15 = lane & 15, l4 = lane >> 4;
  const int swz = (l15 & 7) << 4;
  const size_t Abase = (size_t)blockIdx.x * 128 * K;
  const size_t Bbase = (size_t)blockIdx.y * 128 * K;

  f32x4 acc[2][8] = {};

  const int srow = (w << 3) + (lane >> 3);
  const int scolb = ((lane & 7) * 16) ^ (((lane >> 3) & 7) << 4);
  const ushort* Agrow = A + Abase + (size_t)srow * K;
  const ushort* Bgrow = Bt + Bbase + (size_t)srow * K;

  auto STAGE = [&](int bf, int k0){
    #pragma unroll
    for (int i = 0; i < 4; ++i){
      __builtin_amdgcn_global_load_lds(
        (const __attribute__((address_space(1))) void*)((const char*)(Agrow + k0 + (size_t)(32*i)*K) + scolb),
        (__attribute__((address_space(3))) void*)((char*)As[bf] + w*1024 + i*4096), 16, 0, 0);
      __builtin_amdgcn_global_load_lds(
        (const __attribute__((address_space(1))) void*)((const char*)(Bgrow + k0 + (size_t)(32*i)*K) + scolb),
        (__attribute__((address_space(3))) void*)((char*)Bs[bf] + w*1024 + i*4096), 16, 0, 0);
    }
  };

  const int nt = K >> 6;
  int cur = 0;
  STAGE(0, 0);
  __syncthreads();

  for (int t = 0; t < nt; ++t){
    if (t + 1 < nt) STAGE(cur ^ 1, (t + 1) * 64);
    #pragma unroll
    for (int kk = 0; kk < 2; ++kk){
      s16x8 af[2], bfr[8];
      #pragma unroll
      for (int m = 0; m < 2; ++m)
        af[m] = *(const s16x8*)((char*)As[cur] + (w*32 + m*16 + l15)*128 + ((kk*64 + l4*16) ^ swz));
      #pragma unroll
      for (int n = 0; n < 8; ++n)
        bfr[n] = *(const s16x8*)((char*)Bs[cur] + (n*16 + l15)*128 + ((kk*64 + l4*16) ^ swz));
      __builtin_amdgcn_s_setprio(1);
      #pragma unroll
      for (int m = 0; m < 2; ++m)
        #pragma unroll
        for (int n = 0; n < 8; ++n)
          acc[m][n] = __builtin_amdgcn_mfma_f32_16x16x32_bf16(af[m], bfr[n], acc[m][n], 0, 0, 0);
      __builtin_amdgcn_s_setprio(0);
    }
    __syncthreads();
    cur ^= 1;
  }

  const int r0 = (int)blockIdx.x * 128 + w * 32;
  const int c0 = (int)blockIdx.y * 128;
  if (EPI == 2){
    float* C = (float*)Cout;
    #pragma unroll
    for (int m = 0; m < 2; ++m)
      #pragma unroll
      for (int r = 0; r < 4; ++r){
        size_t rowoff = (size_t)(r0 + m*16 + l4*4 + r) * N + c0;
        #pragma unroll
        for (int n = 0; n < 8; ++n)
          C[rowoff + n*16 + l15] = acc[m][n][r];
      }
  } else if (EPI == 0){
    ushort* C = (ushort*)Cout;
    #pragma unroll
    for (int m = 0; m < 2; ++m)
      #pragma unroll
      for (int r = 0; r < 4; ++r){
        size_t rowoff = (size_t)(r0 + m*16 + l4*4 + r) * N + c0;
        #pragma unroll
        for (int n = 0; n < 8; ++n)
          C[rowoff + n*16 + l15] = f2bf(acc[m][n][r]);
      }
  } else if (EPI == 3 && c0 >= 1024){
    const int kvh = (c0 - 1024) >> 7;
    #pragma unroll
    for (int m = 0; m < 2; ++m){
      int row0 = r0 + m*16 + l4*4;
      int b = row0 >> 11, s = row0 & (S_LEN - 1);
      ushort* vbase = Vt + ((size_t)(b*NKVH + kvh) * HDIM) * S_LEN + s;
      #pragma unroll
      for (int n = 0; n < 8; ++n){
        s16x4 pk;
        #pragma unroll
        for (int r = 0; r < 4; ++r) pk[r] = (short)f2bf(acc[m][n][r]);
        *(s16x4*)(vbase + (size_t)(n*16 + l15) * S_LEN) = pk;
      }
    }
  } else {
    ushort* C = (ushort*)Cout;
    #pragma unroll
    for (int m = 0; m < 2; ++m)
      #pragma unroll
      for (int r = 0; r < 4; ++r){
        int row = r0 + m*16 + l4*4 + r;
        int pos = row & (S_LEN - 1);
        size_t rowoff = (size_t)row * N + c0;
        #pragma unroll
        for (int n = 0; n < 4; ++n){
          int d = n*16 + l15;
          float cv = cost[pos*64 + d];
          float sv = sint[pos*64 + d];
          float x1 = acc[m][n][r];
          float x2 = acc[m][n+4][r];
          C[rowoff + d]      = f2bf((x1*cv - x2*sv) * oscale);
          C[rowoff + d + 64] = f2bf((x2*cv + x1*sv) * oscale);
        }
      }
  }
}

// ---------------- 256x256 8-phase GEMM (T2+T3+T4+T5), depth-3 prefetch, 1 barrier/phase ----------------
// Column remap: wave wn's four n-blocks cover cols (wn>>1)*128 + (wn&1)*32 + {0,16,64,80},
// so RoPE partners (d, d+64) are both in-wave (acc[m][n] / acc[m][n+2]) -> EPI=1 needs no
// LDS exchange and no epilogue barriers. Bijective over the 256-col tile; LDB rows remain
// 16-consecutive per l15 (bank pattern unchanged).
template<int EPI>
__global__ __launch_bounds__(512, 2)
void gemm256(const ushort* __restrict__ A, const ushort* __restrict__ Bt,
             void* __restrict__ Cout, int M, int N, int K,
             const float* __restrict__ cost, const float* __restrict__ sint,
             float oscale)
{
  extern __shared__ char L[];                 // 131072 B
  const int tid = threadIdx.x;
  const int wid = tid >> 6, lane = tid & 63;
  const int wm = wid >> 2, wn = wid & 3;
  const int l15 = lane & 15, l4 = lane >> 4;
  const int swz = (l15 & 7) << 4;
  const int nwg  = gridDim.x;
  const int bid  = blockIdx.x;
  const int sbid = (bid & 7) * (nwg >> 3) + (bid >> 3);
  const int gx   = sbid & 15, gy = sbid >> 4;
  const int brow = gx * 256, bcol = gy * 256;
  const int nt = K >> 6;
  const int nbase = (wn >> 1)*128 + (wn & 1)*32;   // wave's column base within 256-tile

  f32x4 acc[8][4] = {};
  s16x8 areg[8], b0reg[4], b1reg[4];

  auto STAGE = [&](int arr, int sh, int bf, int tile){
    int tt = tile < nt ? tile : nt - 1;
    const ushort* gb = arr ? (Bt + (size_t)bcol * K) : (A + (size_t)brow * K);
    char* lb = L + bf*65536 + arr*32768;
    #pragma unroll
    for (int j = 0; j < 2; ++j){
      int c   = j*8 + wid;
      int rg0 = (c >= 8 ? 128 : 0) + sh*64 + ((c*8) & 63);
      int rg  = rg0 + (lane >> 3);
      const char* gsrc = (const char*)(gb + (size_t)rg * K + tt*64)
                       + (((lane & 7) * 16) ^ (((lane >> 3) & 7) << 4));
      __builtin_amdgcn_global_load_lds(
        (const __attribute__((address_space(1))) void*)gsrc,
        (__attribute__((address_space(3))) void*)(lb + rg0*128), 16, 0, 0);
    }
  };
  auto LDA = [&](int bf, int mh){
    const char* ab = L + bf*65536;
    #pragma unroll
    for (int i = 0; i < 4; ++i){
      int row = wm*128 + (mh*4 + i)*16 + l15;
      #pragma unroll
      for (int kk = 0; kk < 2; ++kk)
        areg[i*2+kk] = *(const s16x8*)(ab + row*128 + ((kk*64 + l4*16) ^ swz));
    }
  };
  auto LDB = [&](int bf, int nh, s16x8* breg){
    const char* bb = L + bf*65536 + 32768;
    #pragma unroll
    for (int j = 0; j < 2; ++j){
      int nb  = nh*2 + j;
      int row = nbase + (nb & 1)*16 + (nb >> 1)*64 + l15;
      #pragma unroll
      for (int kk = 0; kk < 2; ++kk)
        breg[j*2+kk] = *(const s16x8*)(bb + row*128 + ((kk*64 + l4*16) ^ swz));
    }
  };
  auto MFMA16 = [&](int mh, int nh, s16x8* breg){
    __builtin_amdgcn_s_setprio(1);
    #pragma unroll
    for (int kk = 0; kk < 2; ++kk)
      #pragma unroll
      for (int i = 0; i < 4; ++i)
        #pragma unroll
        for (int j = 0; j < 2; ++j)
          acc[mh*4+i][nh*2+j] = __builtin_amdgcn_mfma_f32_16x16x32_bf16(
              areg[i*2+kk], breg[j*2+kk], acc[mh*4+i][nh*2+j], 0, 0, 0);
    __builtin_amdgcn_s_setprio(0);
  };

  STAGE(0,0,0,0); STAGE(1,0,0,0); STAGE(0,1,0,0); STAGE(1,1,0,0);
  STAGE(0,0,1,1); STAGE(1,0,1,1); STAGE(0,1,1,1);
  asm volatile("s_waitcnt vmcnt(6)" ::: "memory");
  __builtin_amdgcn_s_barrier();

  for (int t = 0; t < nt; t += 2){
    LDA(0,0); LDB(0,0,b0reg); STAGE(1,1,1,t+1);
    __builtin_amdgcn_s_barrier();
    MFMA16(0,0,b0reg);
    LDB(0,1,b1reg); STAGE(0,0,0,t+2);
    __builtin_amdgcn_s_barrier();
    MFMA16(0,1,b1reg);
    LDA(0,1); STAGE(1,0,0,t+2);
    __builtin_amdgcn_s_barrier();
    MFMA16(1,0,b0reg);
    STAGE(0,1,0,t+2);
    asm volatile("s_waitcnt vmcnt(6)" ::: "memory");
    __builtin_amdgcn_s_barrier();
    MFMA16(1,1,b1reg);
    LDA(1,0); LDB(1,0,b0reg); STAGE(1,1,0,t+2);
    __builtin_amdgcn_s_barrier();
    MFMA16(0,0,b0reg);
    LDB(1,1,b1reg); STAGE(0,0,1,t+3);
    __builtin_amdgcn_s_barrier();
    MFMA16(0,1,b1reg);
    LDA(1,1); STAGE(1,0,1,t+3);
    __builtin_amdgcn_s_barrier();
    MFMA16(1,0,b0reg);
    STAGE(0,1,1,t+3);
    asm volatile("s_waitcnt vmcnt(6)" ::: "memory");
    __builtin_amdgcn_s_barrier();
    MFMA16(1,1,b1reg);
  }
  asm volatile("s_waitcnt vmcnt(0)" ::: "memory");
  __builtin_amdgcn_s_barrier();

  if (EPI == 2){
    float* C = (float*)Cout;
    #pragma unroll
    for (int m = 0; m < 8; ++m)
      #pragma unroll
      for (int r = 0; r < 4; ++r){
        size_t rowoff = (size_t)(brow + wm*128 + m*16 + l4*4 + r) * N + bcol + nbase + l15;
        #pragma unroll
        for (int n = 0; n < 4; ++n)
          C[rowoff + (n & 1)*16 + (n >> 1)*64] = acc[m][n][r];
      }
  } else {
    // in-wave RoPE: x1 = acc[m][n] (d in 0..63), x2 = acc[m][n+2] (d+64), n in {0,1}
    ushort* C = (ushort*)Cout;
    const int hb = bcol + (wn >> 1)*128;       // head base column
    #pragma unroll
    for (int m = 0; m < 8; ++m)
      #pragma unroll
      for (int r = 0; r < 4; ++r){
        int rr = brow + wm*128 + m*16 + l4*4 + r;
        int pos = rr & (S_LEN - 1);
        size_t rowoff = (size_t)rr * N + hb;
        #pragma unroll
        for (int n = 0; n < 2; ++n){
          int d2 = (wn & 1)*32 + n*16 + l15;  // 0..63
          float cv = cost[pos*64 + d2];
          float sv = sint[pos*64 + d2];
          float x1 = acc[m][n][r];
          float x2 = acc[m][n+2][r];
          C[rowoff + d2]      = f2bf((x1*cv - x2*sv) * oscale);
          C[rowoff + d2 + 64] = f2bf((x2*cv + x1*sv) * oscale);
        }
      }
  }
}

// ---------------- causal GQA flash attention, LDS-staged double-buffered (two-pass) ----------------
__global__ __launch_bounds__(256, 2)
void attn_k(const ushort* __restrict__ Q, const ushort* __restrict__ KVb,
            const ushort* __restrict__ Vt, ushort* __restrict__ AO)
{
  extern __shared__ char L[];
  const int tid = threadIdx.x, w = tid >> 6, lane = tid & 63;
  const int l15 = lane & 15, l4 = lane >> 4;
  const int swz = (l15 & 7) << 4;

  const int id  = blockIdx.x;
  const int idx = id >> 3;
  const int bk  = (id & 7) * 2 + (idx & 1);   // b*8 + kvh
  const int b   = bk >> 3, kvh = bk & 7;
  const int h   = kvh * 4 + ((idx >> 1) & 3);
  const int pair= idx >> 3;                   // 0..7 -> q-tiles {pair, 15-pair}

  const char* Kgb = (const char*)(KVb + (size_t)b * S_LEN * 2048 + kvh * HDIM);
  const char* Vgb = (const char*)(Vt + (size_t)bk * HDIM * S_LEN);
  char* pb = L + 65536 + w*4096;

  const int krow_in = lane >> 4;
  const int kbyte   = l15 * 16;
  const int vrow_in = lane >> 3;
  const int vbyte   = (lane & 7) * 16;

  auto STAGE = [&](int kv0, int bf){
    char* kb = L + bf*32768;
    char* vb = kb + 16384;
    #pragma unroll
    for (int i = 0; i < 4; ++i){
      int c = w*4 + i;
      int krow = c*4 + krow_in;
      const char* ksrc = Kgb + (size_t)(kv0 + krow) * 4096 + (kbyte ^ ((krow & 7) << 4));
      __builtin_amdgcn_global_load_lds(
        (const __attribute__((address_space(1))) void*)ksrc,
        (__attribute__((address_space(3))) void*)(kb + c*1024), 16, 0, 0);
      int vrow = c*8 + vrow_in;
      const char* vsrc = Vgb + (size_t)vrow * (S_LEN*2) + kv0*2 + (vbyte ^ ((vrow & 7) << 4));
      __builtin_amdgcn_global_load_lds(
        (const __attribute__((address_space(1))) void*)vsrc,
        (__attribute__((address_space(3))) void*)(vb + c*1024), 16, 0, 0);
    }
  };

  #pragma unroll
  for (int half = 0; half < 2; ++half){
    const int qt  = half ? (15 - pair) : pair;
    const int wq0 = qt * 128 + w * 32;
    const int nt  = 2*qt + 2;

    s16x8 qf[2][4];
    #pragma unroll
    for (int m = 0; m < 2; ++m){
      const ushort* qp = Q + (size_t)(b*S_LEN + wq0 + m*16 + l15) * (NHEAD*HDIM) + h*HDIM + l4*8;
      #pragma unroll
      for (int kk = 0; kk < 4; ++kk)
        qf[m][kk] = *(const s16x8*)(qp + kk*32);
    }

    float mreg0 = -1e30f, mreg1 = -1e30f, lreg0 = 0.f, lreg1 = 0.f;
    f32x4 oacc[2][8] = {};
    const int qlane0 = wq0 + l15, qlane1 = qlane0 + 16;

    int cur = 0;
    STAGE(0, 0);
    __syncthreads();

    for (int t = 0; t < nt; ++t){
      const int kv0 = t * 64;
      if (t + 1 < nt) STAGE(kv0 + 64, cur ^ 1);
      if (kv0 <= wq0 + 31){
        const char* kb = L + cur*32768;
        const char* vb = kb + 16384;
        f32x4 st[4][2] = {};
        #pragma unroll
        for (int kk = 0; kk < 4; ++kk){
          s16x8 kf[4];
          #pragma unroll
          for (int i = 0; i < 4; ++i){
            int row = i*16 + l15;
            kf[i] = *(const s16x8*)(kb + row*256 + ((kk*64 + l4*16) ^ swz));
          }
          __builtin_amdgcn_s_setprio(1);
          #pragma unroll
          for (int i = 0; i < 4; ++i){
            st[i][0] = __builtin_amdgcn_mfma_f32_16x16x32_bf16(kf[i], qf[0][kk], st[i][0], 0, 0, 0);
            st[i][1] = __builtin_amdgcn_mfma_f32_16x16x32_bf16(kf[i], qf[1][kk], st[i][1], 0, 0, 0);
          }
          __builtin_amdgcn_s_setprio(0);
        }
        if (kv0 + 63 > wq0){
          #pragma unroll
          for (int i = 0; i < 4; ++i){
            int kvb = kv0 + i*16 + l4*4;
            #pragma unroll
            for (int r = 0; r < 4; ++r){
              if (kvb + r > qlane0) st[i][0][r] = -1e30f;
              if (kvb + r > qlane1) st[i][1][r] = -1e30f;
            }
          }
        }
        float mx0 = -1e30f, mx1 = -1e30f;
        #pragma unroll
        for (int i = 0; i < 4; ++i){
          mx0 = fmaxf(mx0, fmaxf(fmaxf(st[i][0][0], st[i][0][1]), fmaxf(st[i][0][2], st[i][0][3])));
          mx1 = fmaxf(mx1, fmaxf(fmaxf(st[i][1][0], st[i][1][1]), fmaxf(st[i][1][2], st[i][1][3])));
        }
        mx0 = fmaxf(mx0, __shfl_xor(mx0, 16)); mx0 = fmaxf(mx0, __shfl_xor(mx0, 32));
        mx1 = fmaxf(mx1, __shfl_xor(mx1, 16)); mx1 = fmaxf(mx1, __shfl_xor(mx1, 32));
        bool resc = !__all((mx0 <= mreg0 + 8.0f) & (mx1 <= mreg1 + 8.0f));
        if (resc){
          float mn0 = fmaxf(mreg0, mx0), mn1 = fmaxf(mreg1, mx1);
          float fs0 = __expf(mreg0 - mn0), fs1 = __expf(mreg1 - mn1);
          mreg0 = mn0; mreg1 = mn1; lreg0 *= fs0; lreg1 *= fs1;
          #pragma unroll
          for (int m = 0; m < 2; ++m){
            float fsm = m ? fs1 : fs0;
            #pragma unroll
            for (int r = 0; r < 4; ++r){
              float fb = __shfl(fsm, (lane & 48) | (l4*4 + r));
              #pragma unroll
              for (int n = 0; n < 8; ++n) oacc[m][n][r] *= fb;
            }
          }
        }
        float s0 = 0.f, s1 = 0.f;
        #pragma unroll
        for (int i = 0; i < 4; ++i){
          int col2 = (i*16 + l4*4) * 2;
          f32x4 p0, p1;
          #pragma unroll
          for (int r = 0; r < 4; ++r){
            p0[r] = __expf(st[i][0][r] - mreg0); s0 += p0[r];
            p1[r] = __expf(st[i][1][r] - mreg1); s1 += p1[r];
          }
          s16x4 u0, u1;
          #pragma unroll
          for (int r = 0; r < 4; ++r){ u0[r] = (short)f2bf(p0[r]); u1[r] = (short)f2bf(p1[r]); }
          *(s16x4*)(pb + ((l15*128 + col2) ^ swz))        = u0;
          *(s16x4*)(pb + (((16 + l15)*128 + col2) ^ swz)) = u1;
        }
        lreg0 += s0; lreg1 += s1;
        #pragma unroll
        for (int kk = 0; kk < 2; ++kk){
          s16x8 pf0 = *(const s16x8*)(pb + ((l15*128 + kk*64 + l4*16) ^ swz));
          s16x8 pf1 = *(const s16x8*)(pb + (((16 + l15)*128 + kk*64 + l4*16) ^ swz));
          s16x8 vf[8];
          #pragma unroll
          for (int n = 0; n < 8; ++n){
            int row = n*16 + l15;
            vf[n] = *(const s16x8*)(vb + row*128 + ((kk*64 + l4*16) ^ swz));
          }
          __builtin_amdgcn_s_setprio(1);
          #pragma unroll
          for (int n = 0; n < 8; ++n){
            oacc[0][n] = __builtin_amdgcn_mfma_f32_16x16x32_bf16(pf0, vf[n], oacc[0][n], 0, 0, 0);
            oacc[1][n] = __builtin_amdgcn_mfma_f32_16x16x32_bf16(pf1, vf[n], oacc[1][n], 0, 0, 0);
          }
          __builtin_amdgcn_s_setprio(0);
        }
      }
      __syncthreads();
      cur ^= 1;
    }

    lreg0 += __shfl_xor(lreg0, 16); lreg0 += __shfl_xor(lreg0, 32);
    lreg1 += __shfl_xor(lreg1, 16); lreg1 += __shfl_xor(lreg1, 32);
    float inv0 = 1.0f / lreg0, inv1 = 1.0f / lreg1;
    #pragma unroll
    for (int m = 0; m < 2; ++m){
      float invm = m ? inv1 : inv0;
      #pragma unroll
      for (int r = 0; r < 4; ++r){
        float ib = __shfl(invm, (lane & 48) | (l4*4 + r));
        ushort* dst = AO + (size_t)(b*S_LEN + wq0 + m*16 + l4*4 + r) * (NHEAD*HDIM) + h*HDIM;
        #pragma unroll
        for (int n = 0; n < 8; ++n)
          dst[n*16 + l15] = f2bf(oacc[m][n][r] * ib);
      }
    }
  }
}

extern "C" void kernel_launch(void* const* d_in, const int* in_sizes, int n_in,
                              void* d_out, int out_size, void* d_ws, size_t ws_size,
                              hipStream_t stream)
{
  const float* X  = (const float*)d_in[0];
  const float* Wq = (const float*)d_in[3];
  const float* Wk = (const float*)d_in[4];
  const float* Wv = (const float*)d_in[5];
  const float* Wo = (const float*)d_in[6];

  char* ws = (char*)d_ws;
  float*  cost = (float*) (ws + 0);           // 512 KB
  float*  sint = (float*) (ws + 524288);      // 512 KB
  ushort* Xb   = (ushort*)(ws + 1048576);     // 33.5 MB
  ushort* WqT  = (ushort*)(ws + 34603008);    // 33.5 MB
  ushort* WkvT = (ushort*)(ws + 68157440);    // 16.8 MB  [2048][4096]
  ushort* Qb   = (ushort*)(ws + 84934656);    // 33.5 MB
  ushort* KVb  = (ushort*)(ws + 118489088);   // 16.8 MB  [4096][2048] (K cols 0..1023 used)
  ushort* Vt   = (ushort*)(ws + 135266304);   // 8.4 MB
  ushort* WoT  = (ushort*)(ws + 143654912);   // 33.5 MB  (end 177209344)
  ushort* AO   = WqT;                         // WqT dead after Q GEMM

  const float qk_scale = 0.08838834764831845f;  // 1/sqrt(128), folded into Q RoPE

  const int GLDS = 131072;
  const int ALDS = 81920;
  hipFuncSetAttribute((const void*)gemm256<1>, hipFuncAttributeMaxDynamicSharedMemorySize, GLDS);
  hipFuncSetAttribute((const void*)gemm256<2>, hipFuncAttributeMaxDynamicSharedMemorySize, GLDS);
  hipFuncSetAttribute((const void*)attn_k,     hipFuncAttributeMaxDynamicSharedMemorySize, ALDS);

  prep_k<<<dim3(64, 288), 256, 0, stream>>>(Wq, Wk, Wv, Wo, WqT, WkvT, WoT, X, Xb, cost, sint);

  gemm256<1><<<256, 512, GLDS, stream>>>(Xb, WqT, Qb, 4096, 4096, 4096, cost, sint, qk_scale);
  gemm_bt<3><<<dim3(32, 16), 256, 0, stream>>>(Xb, WkvT, KVb, 4096, 2048, 4096, cost, sint, 1.0f, Vt);

  attn_k<<<512, 256, ALDS, stream>>>(Qb, KVb, Vt, AO);

  gemm256<2><<<256, 512, GLDS, stream>>>(AO, WoT, d_out, 4096, 4096, 4096, nullptr, nullptr, 1.0f);
}